// Round 10
// baseline (713.123 us; speedup 1.0000x reference)
//
#include <hip/hip_runtime.h>
#include <math.h>

#define R_ 64
#define S_ 32
#define W_ 64
#define H_ 256
#define UF_ 20
#define TC 4        // time-chunk for path B

typedef short bf16x8 __attribute__((ext_vector_type(8)));
typedef float f32x4  __attribute__((ext_vector_type(4)));

#define MFMA(a,b,c) __builtin_amdgcn_mfma_f32_16x16x32_bf16((a),(b),(c),0,0,0)

typedef const unsigned int __attribute__((address_space(1)))* gp_t;
typedef unsigned int __attribute__((address_space(3)))* lp_t;
// async global->LDS DMA, 16B per lane, dest = wave-uniform base + lane*16
#define GLOAD16(SRC, DST) \
  __builtin_amdgcn_global_load_lds((gp_t)(const void*)(SRC), (lp_t)(void*)(DST), 16, 0, 0)

// hbf bank swizzle (rev_gru only)
#define SW(r) ((((r)>>1)&7)<<3)

// whh fragment ff: 0..39 register-resident, 40..47 in LDS (Bl)
#define BFRAG(ff) ((ff) < 40 ? Breg[(ff) < 40 ? (ff) : 0] \
                 : *(const bf16x8*)&Bl[w][(ff) >= 40 ? (ff)-40 : 0][l*8])

__device__ __forceinline__ float sigf(float x){ return 1.0f/(1.0f+__expf(-x)); }
__device__ __forceinline__ float tanhf_(float x){ float e=__expf(2.0f*x); return 1.0f-2.0f/(e+1.0f); }
__device__ __forceinline__ float seluf_(float x){
  const float sc=1.0507009873554805f, al=1.6732632423543772f;
  return x>0.0f ? sc*x : sc*al*(expf(x)-1.0f);
}
__device__ __forceinline__ short tobf(float f){
  unsigned u=__float_as_uint(f); u += 0x7fffu + ((u>>16)&1u); return (short)(u>>16);
}
__device__ __forceinline__ float bf2f(short s){
  return __uint_as_float(((unsigned)(unsigned short)s) << 16);
}
__device__ __forceinline__ unsigned pk2(float a, float b){
  return (unsigned)(unsigned short)tobf(a) | ((unsigned)(unsigned short)tobf(b) << 16);
}

// ---------------------------------------------------------------------------
// Weight-prep bodies (merged into one launch below)
// ---------------------------------------------------------------------------
__device__ __forceinline__ void prep_word_body(int idx, const float* wih,
                                               const float* whh, short* Bw)
{
  int lane = idx & 63;
  int rest = idx >> 6;
  int f  = rest % 6;  rest /= 6;
  int kt = rest % 16; rest /= 16;
  int w  = rest % 8;
  int d  = rest / 8;
  int gate = f >> 1;
  int j = 32*w + (f&1)*16 + (lane&15);
  int row = gate*256 + j;
  const float* W = (kt < 8 ? wih : whh) + (size_t)d*768*256;
  int k = (kt&7)*32 + (lane>>4)*8;
  short* dst = Bw + ((((size_t)(d*8 + w)*16 + kt)*6 + f)*64 + lane)*8;
#pragma unroll
  for (int jj=0;jj<8;jj++) dst[jj] = tobf(W[(size_t)row*256 + k + jj]);
}

__device__ __forceinline__ void prep_rnn_body(int idx, const float* whh, short* Bs)
{
  int lane = idx & 63;
  int rest = idx >> 6;
  int f  = rest % 6; rest /= 6;
  int kt = rest % 8; rest /= 8;
  int w  = rest % 8;
  int d  = rest / 8;
  int j = 32*w + (f&1)*16 + (lane&15);
  int row = (f>>1)*256 + j;
  const float* W = whh + (size_t)d*768*256;
  int k = kt*32 + (lane>>4)*8;
  short* dst = Bs + ((((size_t)(d*8 + w)*8 + kt)*6 + f)*64 + lane)*8;
#pragma unroll
  for (int jj=0;jj<8;jj++) dst[jj] = tobf(W[(size_t)row*256 + k + jj]);
}

__device__ __forceinline__ void prep_gemm_body(int idx, const float* Wsrc, short* Bg)
{
  int lane = idx & 63;
  int rest = idx >> 6;
  int kt = rest % 8;
  int nt = rest / 8;
  int n = nt*16 + (lane&15);
  int k = kt*32 + (lane>>4)*8;
  short* dst = Bg + (((size_t)nt*8 + kt)*64 + lane)*8;
#pragma unroll
  for (int jj=0;jj<8;jj++) dst[jj] = tobf(Wsrc[(size_t)n*256 + k + jj]);
}

__device__ __forceinline__ void prep_embb_body(int t, const float* E, short* O, int M)
{
  const int row = t >> 5, c0 = (t & 31)*8;
  const int r = row < M ? row : M - 1;
  const float* s = E + (size_t)r*256 + c0;
  float4 v0 = *(const float4*)(s);
  float4 v1 = *(const float4*)(s + 4);
  uint4 u;
  u.x = pk2(v0.x, v0.y); u.y = pk2(v0.z, v0.w);
  u.z = pk2(v1.x, v1.y); u.w = pk2(v1.z, v1.w);
  *(uint4*)&O[(size_t)row*256 + c0] = u;
}

// One launch for all weight preps + optional embed->bf16 convert.
// Block ranges: [0,384) word, [384,576) sent-rnn, [576,768) rev-rnn,
// [768,960) sent-gemm, [960,1152) word-gemm, [1152,1152+6256) embb.
__global__ void prep_all(const float* __restrict__ wg_wih, const float* __restrict__ wg_whh,
                         const float* __restrict__ sg_whh, const float* __restrict__ rg_whh,
                         const float* __restrict__ sg_wih, const float* __restrict__ embed,
                         short* __restrict__ Bw, short* __restrict__ Bs,
                         short* __restrict__ Br, short* __restrict__ Bg,
                         short* __restrict__ Bgw, short* __restrict__ embb)
{
  const int b = blockIdx.x, tid = threadIdx.x;
  if      (b <  384) prep_word_body( b       *256 + tid, wg_wih, wg_whh, Bw);
  else if (b <  576) prep_rnn_body ((b- 384)*256 + tid, sg_whh, Bs);
  else if (b <  768) prep_rnn_body ((b- 576)*256 + tid, rg_whh, Br);
  else if (b <  960) prep_gemm_body((b- 768)*256 + tid, sg_wih, Bg);
  else if (b < 1152) prep_gemm_body((b- 960)*256 + tid, wg_wih, Bgw);
  else               prep_embb_body((b-1152)*256 + tid, embed, embb, 50000);
}

// ---------------------------------------------------------------------------
// Unified MFMA gx GEMM, C bf16 = A[.,256] @ B^T + bias. Tile 64x128, 256 thr.
// mode 0: A = bf16 contiguous rows (Ab)           (vocab embb)
// mode 1: A = fp32 rows of Af, clamped to Mclamp  (vocab fallback)
// mode 2: A = fp32 rows of Af gathered via token window (chunked, path B)
// mode 3: A = fp32 dir-sum rows: Af[r] + Af[r + 2048*256] (sentence gx,
//         folds the old add2bf kernel into the staging)
// swapxy=1 transposes the grid mapping (x=yt fast, y=m-tile): same-A blocks
// become dispatch-adjacent and each XCD sees only ~3 of 12 B panels ->
// better L2/L3 locality against the C-write churn (r7 counter evidence).
// ---------------------------------------------------------------------------
__global__ __launch_bounds__(256) void gemm_gxu(
    const short* __restrict__ Ab, const float* __restrict__ Af,
    const int* __restrict__ toks, const short* __restrict__ Bg,
    const float* __restrict__ bih, const float* __restrict__ bhh,
    short* __restrict__ C, long Czoff,
    int mode, int t0, int Mclamp, int Cstride, int swapxy)
{
  const int z  = blockIdx.z;
  const int bx = swapxy ? blockIdx.y : blockIdx.x;
  const int by = swapxy ? blockIdx.x : blockIdx.y;
  const int m0 = bx * 64;
  const int yt = by * 8;                            // C ntile base (dir-local)
  const int ntb = (mode == 2 ? z*48 : 0) + yt;      // B ntile base
  const int tid = threadIdx.x;
  const int w = tid >> 6, l = tid & 63;
  const int c = l & 15, q = l >> 4;
  __shared__ short As[64][264];
  {
    const int row = tid >> 2, c0 = (tid & 3) * 64;
    if (mode == 0) {
      const uint4* s = (const uint4*)(Ab + (size_t)(m0+row)*256 + c0);
#pragma unroll
      for (int i = 0; i < 8; i++) *(uint4*)&As[row][c0 + i*8] = s[i];
    } else if (mode == 3) {
      const float* s0 = Af + (size_t)(m0+row)*256 + c0;
      const float* s1 = s0 + (size_t)2048*256;
#pragma unroll
      for (int i = 0; i < 8; i++) {
        float4 a0 = *(const float4*)(s0 + i*8);
        float4 a1 = *(const float4*)(s0 + i*8 + 4);
        float4 b0 = *(const float4*)(s1 + i*8);
        float4 b1 = *(const float4*)(s1 + i*8 + 4);
        uint4 u;
        u.x = pk2(a0.x+b0.x, a0.y+b0.y); u.y = pk2(a0.z+b0.z, a0.w+b0.w);
        u.z = pk2(a1.x+b1.x, a1.y+b1.y); u.w = pk2(a1.z+b1.z, a1.w+b1.w);
        *(uint4*)&As[row][c0 + i*8] = u;
      }
    } else {
      int r;
      if (mode == 1) {
        r = m0 + row; if (r >= Mclamp) r = Mclamp - 1;
      } else {
        const int rr = m0 + row;
        const int s_ = rr / TC, i_ = rr % TC;
        const int wd = z ? (63 - (t0 + i_)) : (t0 + i_);
        r = toks[s_*64 + wd];
      }
      const float* s = Af + (size_t)r*256 + c0;
#pragma unroll
      for (int i = 0; i < 8; i++) {
        float4 v0 = *(const float4*)(s + i*8);
        float4 v1 = *(const float4*)(s + i*8 + 4);
        uint4 u;
        u.x = pk2(v0.x, v0.y); u.y = pk2(v0.z, v0.w);
        u.z = pk2(v1.x, v1.y); u.w = pk2(v1.z, v1.w);
        *(uint4*)&As[row][c0 + i*8] = u;
      }
    }
  }
  // per-thread bias for its 2 output columns
  float bias[2];
#pragma unroll
  for (int nt = 0; nt < 2; nt++) {
    const int coln = (yt + 2*w + nt)*16 + c;               // dir-local col
    const int bidx = (mode == 2 ? z*768 : 0) + coln;       // global col
    bias[nt] = bih[bidx] + ((bidx % 768) < 512 ? bhh[bidx] : 0.0f);
  }
  __syncthreads();
  f32x4 acc[4][2];
#pragma unroll
  for (int a = 0; a < 4; a++) { acc[a][0] = (f32x4)0.f; acc[a][1] = (f32x4)0.f; }
#pragma unroll
  for (int kt = 0; kt < 8; kt++) {
    const int ko = kt*32 + q*8;
    bf16x8 a0 = *(const bf16x8*)&As[ 0+c][ko];
    bf16x8 a1 = *(const bf16x8*)&As[16+c][ko];
    bf16x8 a2 = *(const bf16x8*)&As[32+c][ko];
    bf16x8 a3 = *(const bf16x8*)&As[48+c][ko];
    bf16x8 b0 = *(const bf16x8*)&Bg[(((size_t)(ntb + 2*w    )*8 + kt)*64 + l)*8];
    bf16x8 b1 = *(const bf16x8*)&Bg[(((size_t)(ntb + 2*w + 1)*8 + kt)*64 + l)*8];
    acc[0][0]=MFMA(a0,b0,acc[0][0]); acc[1][0]=MFMA(a1,b0,acc[1][0]);
    acc[2][0]=MFMA(a2,b0,acc[2][0]); acc[3][0]=MFMA(a3,b0,acc[3][0]);
    acc[0][1]=MFMA(a0,b1,acc[0][1]); acc[1][1]=MFMA(a1,b1,acc[1][1]);
    acc[2][1]=MFMA(a2,b1,acc[2][1]); acc[3][1]=MFMA(a3,b1,acc[3][1]);
  }
  short* Cz = C + (size_t)z * Czoff;
#pragma unroll
  for (int mt = 0; mt < 4; mt++)
#pragma unroll
  for (int nt = 0; nt < 2; nt++)
#pragma unroll
  for (int rg = 0; rg < 4; rg++)
    Cz[(size_t)(m0 + mt*16 + q*4 + rg)*Cstride + (yt + 2*w + nt)*16 + c] =
        tobf(acc[mt][nt][rg] + bias[nt]);
}

// ---------------------------------------------------------------------------
// gx staging DMA (r1 layout): wave w stages its row pair {2w, 2w+1}
// (2 x 1536B) of step tt into gbuf[buf] rows 2w,2w+1 (contiguous, unpadded).
// ---------------------------------------------------------------------------
__device__ __forceinline__ void stage_issue(
    short* dstbase,                 // &gbuf[buf][0][0]
    int mode, int d, int g, int w, int l,
    int nwords, int t0, int tt,
    const int* tokp, const short* gxF, const short* gxB)
{
  const char* bF = (const char*)gxF;
  const char* bB = (const char*)gxB;
#pragma unroll
  for (int i = 0; i < 3; i++) {
    const int off = i*1024 + l*16;          // byte within row pair (0..3071)
    const int rl  = (off >= 1536) ? 1 : 0;  // row within pair
    const int col = off - rl*1536;          // byte within row
    const char* src;
    if (mode == 0) {
      const int tx  = d ? (nwords - 1 - tt) : tt;
      const int tok = tokp[(2*w + rl)*64 + tx];
      src = bF + (size_t)tok*3072 + d*1536 + col;
    } else if (mode == 1) {
      const int ri = (g*16 + 2*w + rl)*TC + (tt - t0);
      src = (d ? bB : bF) + (size_t)ri*1536 + col;
    } else {
      const int se  = d ? (nwords - 1 - tt) : tt;
      const int row = g*16 + 2*w + rl;
      src = bF + ((size_t)row*nwords + se)*3072 + (size_t)d*1536 + col;
    }
    GLOAD16(src, dstbase + (size_t)w*1536 + i*512);
  }
}

// ---------------------------------------------------------------------------
// Unified bi-GRU recurrence — r1-verified structure (best measured: 222 µs)
// + bias folding (only bNH remains in-loop). whh fragments: 40 in registers,
// 8 in LDS. gx staged via async DMA issued ONE STEP AHEAD; __syncthreads'
// implicit vmcnt drain is the completion guarantee. Inline per-kt fragment
// reads and inline gbuf epilogue reads keep mid-loop register liveness
// minimal (the r2-r4 regressions came from preload arrays raising pressure).
// Block = (dir, group of 16 rows); 512 thr / 8 waves; one barrier per step.
// ---------------------------------------------------------------------------
__global__ __launch_bounds__(512, 2) void gru_rec(
    const int* __restrict__ toks,
    const short* __restrict__ gxF, const short* __restrict__ gxB,
    const short* __restrict__ Bh, int wstride, int koff,
    const float* __restrict__ bhh,
    float* __restrict__ hstate, int NS,
    int t0, int nsteps, int mode, int nwords)
{
  const int d = blockIdx.x & 1;
  const int g = blockIdx.x >> 1;
  const int tid = threadIdx.x;
  const int w = tid >> 6, l = tid & 63;
  const int c = l & 15, q = l >> 4;

  __shared__ short gbuf[2][16][768];    // UNPADDED: DMA dest must be linear
  __shared__ short hbf[2][16][264];
  __shared__ short Bl[8][8][512];       // whh fragments ff=40..47, per wave
  __shared__ int   tokL[1024];

  if (mode == 0)
    for (int i = tid; i < 1024; i += 512) tokL[i] = toks[(size_t)g*1024 + i];

  // whh fragments: 40 in registers, 8 in LDS
  bf16x8 Breg[40];
  {
    const short* Bb = Bh + (size_t)(d*8 + w)*wstride + (size_t)koff*3072 + l*8;
#pragma unroll
    for (int ff = 0; ff < 48; ff++) {
      bf16x8 v = *(const bf16x8*)(Bb + ff*512);
      if (ff < 40) Breg[ff] = v;
      else *(bf16x8*)&Bl[w][ff-40][l*8] = v;
    }
  }

  float bNH[2];
#pragma unroll
  for (int jt = 0; jt < 2; jt++)
    bNH[jt] = bhh[d*768 + 512 + 32*w + jt*16 + c];

  float hst[2][4];
  const int cur0 = t0 & 1;
  if (t0 == 0) {
#pragma unroll
    for (int a = 0; a < 2; a++)
#pragma unroll
    for (int r = 0; r < 4; r++) hst[a][r] = 0.0f;
  } else {
#pragma unroll
    for (int jt = 0; jt < 2; jt++)
#pragma unroll
    for (int rg = 0; rg < 4; rg++)
      hst[jt][rg] = hstate[((size_t)d*NS + g*16 + q*4 + rg)*256 + 32*w + jt*16 + c];
  }
#pragma unroll
  for (int jt = 0; jt < 2; jt++)
#pragma unroll
  for (int rg = 0; rg < 4; rg++)
    hbf[cur0][q*4 + rg][32*w + jt*16 + c] = tobf(hst[jt][rg]);

  // prologue stage of step t0 (mode 0 reads tokens from global; tokL not
  // yet visible before the barrier)
  stage_issue((short*)gbuf[cur0], mode, d, g, w, l, nwords, t0, t0,
              (mode == 0) ? toks + (size_t)g*1024 : (const int*)nullptr, gxF, gxB);

  __syncthreads();   // tokL + hbf + Bl init + prologue DMA all visible

  const int tend = t0 + nsteps;
  for (int t = t0; t < tend; t++) {
    const int cur = t & 1, nxt = 1 - cur;

    // issue NEXT step's gx DMA now; it completes during MFMA+epilogue and
    // the end-of-iter __syncthreads (vmcnt drain) guarantees visibility.
    if (t + 1 < tend)
      stage_issue((short*)gbuf[nxt], mode, d, g, w, l, nwords, t0, t + 1,
                  tokL, gxF, gxB);

    f32x4 accR[2], accZ[2], accNH[2];
#pragma unroll
    for (int a = 0; a < 2; a++) { accR[a]=(f32x4)0.f; accZ[a]=(f32x4)0.f; accNH[a]=(f32x4)0.f; }
#pragma unroll
    for (int kt = 0; kt < 8; kt++) {
      bf16x8 a0 = *(const bf16x8*)&hbf[cur][c][kt*32 + q*8];
      bf16x8 b0 = BFRAG(kt*6+0), b1 = BFRAG(kt*6+1), b2 = BFRAG(kt*6+2),
             b3 = BFRAG(kt*6+3), b4 = BFRAG(kt*6+4), b5 = BFRAG(kt*6+5);
      accR[0]=MFMA(a0,b0,accR[0]);  accR[1]=MFMA(a0,b1,accR[1]);
      accZ[0]=MFMA(a0,b2,accZ[0]);  accZ[1]=MFMA(a0,b3,accZ[1]);
      accNH[0]=MFMA(a0,b4,accNH[0]); accNH[1]=MFMA(a0,b5,accNH[1]);
    }

    // gates + state update (biases pre-folded into gx except bNH)
#pragma unroll
    for (int jt = 0; jt < 2; jt++)
#pragma unroll
    for (int rg = 0; rg < 4; rg++) {
      const int m = q*4 + rg;
      const int j = 32*w + jt*16 + c;
      const float gr = bf2f(gbuf[cur][m][j]);
      const float gz = bf2f(gbuf[cur][m][256 + j]);
      const float gn = bf2f(gbuf[cur][m][512 + j]);
      const float r = sigf(gr + accR[jt][rg]);
      const float z = sigf(gz + accZ[jt][rg]);
      const float n = tanhf_(gn + r*(accNH[jt][rg] + bNH[jt]));
      float h = hst[jt][rg];
      h = (1.0f - z)*n + z*h;
      hst[jt][rg] = h;
      hbf[nxt][m][j] = tobf(h);
    }
    __syncthreads();   // drains next-step DMA (vmcnt) + hbf[nxt] (lgkm)
  }

#pragma unroll
  for (int jt = 0; jt < 2; jt++)
#pragma unroll
  for (int rg = 0; rg < 4; rg++)
    hstate[((size_t)d*NS + g*16 + q*4 + rg)*256 + 32*w + jt*16 + c] = hst[jt][rg];
}

// ---------------------------------------------------------------------------
// Review-level bi-GRU, batch 1. Only row 0 is real: epilogue on q==0 lanes,
// hbf double-buffered -> single barrier per step. Biases pre-folded (bNH
// only). Grid 2.
// ---------------------------------------------------------------------------
__global__ __launch_bounds__(512, 2) void rev_gru(
    const float* __restrict__ gx, const short* __restrict__ Br,
    const float* __restrict__ bhh,
    float* __restrict__ doc)
{
  const int d = blockIdx.x;
  const int tid = threadIdx.x;
  const int w = tid >> 6, l = tid & 63;
  const int c = l & 15, q = l >> 4;
  const int j0 = 32*w + c;

  __shared__ short hbf[2][16][256];   // swizzled; rows >=1 stay zero
  __shared__ short Bl[8][8][512];
  for (int i = tid; i < 2*16*256; i += 512) ((short*)hbf)[i] = 0;

  bf16x8 Breg[40];
  {
    const short* Bbase = Br + (size_t)(d*8 + w)*8*6*512 + l*8;
#pragma unroll
    for (int ff = 0; ff < 48; ff++) {
      bf16x8 v = *(const bf16x8*)(Bbase + ff*512);
      if (ff < 40) Breg[ff] = v;
      else *(bf16x8*)&Bl[w][ff-40][l*8] = v;
    }
  }

  float bNH[2];
#pragma unroll
  for (int jt = 0; jt < 2; jt++)
    bNH[jt] = bhh[d*768 + 512 + j0 + jt*16];

  float hst[2];
  hst[0] = 0.0f; hst[1] = 0.0f;
  __syncthreads();

  for (int t = 0; t < 64; t++) {
    const int cur = t & 1, nxt = 1 - cur;
    const int teff = (d == 0) ? t : (63 - t);

    // prefetch this step's gates (row 0 only -> q==0 lanes)
    float G[2][3];
    if (q == 0) {
#pragma unroll
      for (int jt = 0; jt < 2; jt++) {
        const size_t row = (size_t)teff*1536 + d*768;
        const int j = j0 + jt*16;
        G[jt][0] = gx[row + j]; G[jt][1] = gx[row + 256 + j]; G[jt][2] = gx[row + 512 + j];
      }
    }

    f32x4 accR[2], accZ[2], accNH[2];
#pragma unroll
    for (int a=0;a<2;a++) { accR[a]=(f32x4)0.f; accZ[a]=(f32x4)0.f; accNH[a]=(f32x4)0.f; }
#pragma unroll
    for (int kt = 0; kt < 8; kt++) {
      bf16x8 a0 = *(const bf16x8*)&hbf[cur][c][(kt*32 + q*8) ^ SW(c)];
      bf16x8 b0 = BFRAG(kt*6+0), b1 = BFRAG(kt*6+1), b2 = BFRAG(kt*6+2),
             b3 = BFRAG(kt*6+3), b4 = BFRAG(kt*6+4), b5 = BFRAG(kt*6+5);
      accR[0]=MFMA(a0,b0,accR[0]);  accR[1]=MFMA(a0,b1,accR[1]);
      accZ[0]=MFMA(a0,b2,accZ[0]);  accZ[1]=MFMA(a0,b3,accZ[1]);
      accNH[0]=MFMA(a0,b4,accNH[0]); accNH[1]=MFMA(a0,b5,accNH[1]);
    }

    if (q == 0) {
#pragma unroll
      for (int jt = 0; jt < 2; jt++) {
        const float r = sigf(G[jt][0] + accR[jt][0]);
        const float z = sigf(G[jt][1] + accZ[jt][0]);
        const float n = tanhf_(G[jt][2] + r*(accNH[jt][0] + bNH[jt]));
        const float h = n + z*(hst[jt] - n);
        hst[jt] = h;
        hbf[nxt][0][j0 + jt*16] = tobf(h);   // row 0: SW(0)=0
      }
    }
    __syncthreads();
  }
  if (q == 0) {
#pragma unroll
    for (int jt = 0; jt < 2; jt++)
      doc[d*256 + j0 + jt*16] = hst[jt];
  }
}

// ---------------------------------------------------------------------------
// Fused p_batch + r_stars + review-level gx GEMM row. Block r:
//   (1) builds pb row r in LDS (ps[276]),
//   (2) computes r_stars[r],
//   (3) computes gxr[r][0:1536] = ps @ rg_wih^T + bias (replaces gemm_nt16;
//       rg_wih is L2-resident after the first blocks warm it).
// ---------------------------------------------------------------------------
__global__ void pbrs_k(const float* __restrict__ hs, const float* __restrict__ uf,
                       const float* __restrict__ ufw,
                       const float* __restrict__ w1, const float* __restrict__ b1,
                       const float* __restrict__ w2, const float* __restrict__ b2,
                       const float* __restrict__ rgw, const float* __restrict__ rgbih,
                       const float* __restrict__ rgbhh,
                       float* __restrict__ gxr, float* __restrict__ out)
{
  const int r = blockIdx.x, tid = threadIdx.x;   // 256 threads
  __shared__ float ps[276];
  __shared__ float s1[128];
  __shared__ float nrm;
  if (tid == 0) {
    float s = 0.f;
    for (int i = 0; i < UF_; i++) { const float v = uf[r*UF_ + i]; s += v*v; }
    nrm = fmaxf(sqrtf(s), 1e-12f);
  }
  __syncthreads();
  if (tid < H_)
    ps[tid] = hs[r*H_ + tid] + hs[(size_t)R_*H_ + r*H_ + tid];
  if (tid < UF_)
    ps[H_ + tid] = uf[r*UF_ + tid] / nrm * ufw[tid];
  __syncthreads();
  // review-level gx row (6 cols per thread)
#pragma unroll
  for (int i = 0; i < 6; i++) {
    const int n = tid + 256*i;
    float a = rgbih[n] + ((n % 768) < 512 ? rgbhh[n] : 0.0f);
    const float* wr = rgw + (size_t)n*276;
    for (int k = 0; k < 276; k++) a += ps[k] * wr[k];
    gxr[(size_t)r*1536 + n] = a;
  }
  // r_stars
  if (tid < 128) {
    float a = b1[tid];
    for (int k = 0; k < 276; k++) a += ps[k] * w1[tid*276 + k];
    s1[tid] = seluf_(a);
  }
  __syncthreads();
  if (tid == 0) {
    float s = b2[0];
    for (int k = 0; k < 128; k++) s += s1[k] * w2[k];
    out[9 + r] = s;
  }
}

// p_stars (doc dir-sum folded in: dc = doc2[0:256] + doc2[256:512])
__global__ void pstars_k(const float* __restrict__ doc2,
                         const float* __restrict__ w1, const float* __restrict__ b1,
                         const float* __restrict__ w2, const float* __restrict__ b2,
                         float* __restrict__ out)
{
  const int tid = threadIdx.x;   // 128 threads
  __shared__ float dc[256];
  __shared__ float s1[128];
  dc[tid]       = doc2[tid]       + doc2[256 + tid];
  dc[128 + tid] = doc2[128 + tid] + doc2[384 + tid];
  __syncthreads();
  float a = b1[tid];
  for (int k = 0; k < 256; k++) a += dc[k] * w1[tid*256 + k];
  s1[tid] = seluf_(a);
  __syncthreads();
  if (tid < 9) {
    float s = b2[tid];
    for (int k = 0; k < 128; k++) s += s1[k] * w2[tid*128 + k];
    out[tid] = s;
  }
}

// ---------------------------------------------------------------------------
extern "C" void kernel_launch(void* const* d_in, const int* in_sizes, int n_in,
                              void* d_out, int out_size, void* d_ws, size_t ws_size,
                              hipStream_t stream)
{
  const int*   toks   = (const int*)  d_in[0];
  const float* uf     = (const float*)d_in[3];
  const float* embed  = (const float*)d_in[4];
  const float* wg_wih = (const float*)d_in[5];
  const float* wg_whh = (const float*)d_in[6];
  const float* wg_bih = (const float*)d_in[7];
  const float* wg_bhh = (const float*)d_in[8];
  const float* sg_wih = (const float*)d_in[9];
  const float* sg_whh = (const float*)d_in[10];
  const float* sg_bih = (const float*)d_in[11];
  const float* sg_bhh = (const float*)d_in[12];
  const float* rg_wih = (const float*)d_in[13];
  const float* rg_whh = (const float*)d_in[14];
  const float* rg_bih = (const float*)d_in[15];
  const float* rg_bhh = (const float*)d_in[16];
  const float* rfc_w1 = (const float*)d_in[17];
  const float* rfc_b1 = (const float*)d_in[18];
  const float* rfc_w2 = (const float*)d_in[19];
  const float* rfc_b2 = (const float*)d_in[20];
  const float* pfc_w1 = (const float*)d_in[21];
  const float* pfc_b1 = (const float*)d_in[22];
  const float* pfc_w2 = (const float*)d_in[23];
  const float* pfc_b2 = (const float*)d_in[24];
  const float* uf_w   = (const float*)d_in[25];
  float* out = (float*)d_out;
  float* ws  = (float*)d_ws;
  (void)in_sizes; (void)n_in; (void)out_size;

  // workspace layout (float offsets)
  const size_t OFF_BW   = 0;                         // 393,216
  const size_t OFF_BS   = OFF_BW  + 393216;          // 196,608
  const size_t OFF_BR   = OFF_BS  + 196608;          // 196,608
  const size_t OFF_BG   = OFF_BR  + 196608;          // 196,608
  const size_t OFF_BGW  = OFF_BG  + 196608;          // 196,608
  const size_t OFF_HF   = OFF_BGW + 196608;          // 1,048,576
  const size_t OFF_SB   = OFF_HF  + 1048576;         // 262,144 (unused, kept)
  const size_t OFF_GXS  = OFF_SB  + 262144;          // 1,572,864 (bf16 2048x1536)
  const size_t OFF_HS   = OFF_GXS + 1572864;         // 32,768
  const size_t OFF_PB   = OFF_HS  + 32768;           // 17,664 (unused, kept)
  const size_t OFF_GXR  = OFF_PB  + 17664;           // 98,304
  const size_t OFF_DOC  = OFF_GXR + 98304;           // 512
  const size_t OFF_GXT  = OFF_DOC + 512;             // B: 2x 8192x768 bf16 = 6,291,456 f
  const size_t TOT_A    = OFF_GXT + (size_t)50048*1536/2;   // gxv bf16
  const size_t OFF_EMB  = TOT_A;                     // embb bf16 50048x256
  const size_t TOT_B    = TOT_A + (size_t)50048*256/2;

  short* Bw   = (short*)(ws + OFF_BW);
  short* Bs   = (short*)(ws + OFF_BS);
  short* Br   = (short*)(ws + OFF_BR);
  short* Bg   = (short*)(ws + OFF_BG);
  short* Bgw  = (short*)(ws + OFF_BGW);
  float* hfin = ws + OFF_HF;
  short* gxs  = (short*)(ws + OFF_GXS);
  float* hs   = ws + OFF_HS;
  float* gxr  = ws + OFF_GXR;
  float* doc  = ws + OFF_DOC;
  short* gxf  = (short*)(ws + OFF_GXT);
  short* gxb  = gxf + (size_t)8192*768;
  short* gxv  = (short*)(ws + OFF_GXT);
  short* embb = (short*)(ws + OFF_EMB);

  const bool bigger = ws_size >= TOT_B * sizeof(float);   // room for embb
  const bool big    = ws_size >= TOT_A * sizeof(float);

  // all weight preps (+ embed->bf16 when used) in ONE launch
  prep_all<<<1152 + (bigger ? 6256 : 0), 256, 0, stream>>>(
      wg_wih, wg_whh, sg_whh, rg_whh, sg_wih, embed,
      Bw, Bs, Br, Bg, Bgw, embb);

  if (big) {
    // path A: per-vocab x-gates (bf16, bias-folded), r5 tile, TRANSPOSED
    // grid (12,782): same-A blocks dispatch-adjacent, per-XCD B set 3/12.
    if (bigger) {
      gemm_gxu<<<dim3(12, 782, 1), 256, 0, stream>>>(
          embb, nullptr, nullptr, Bgw, wg_bih, wg_bhh, gxv, 0, 0, 0, 0, 1536, 1);
    } else {
      gemm_gxu<<<dim3(12, 782, 1), 256, 0, stream>>>(
          nullptr, embed, nullptr, Bgw, wg_bih, wg_bhh, gxv, 0, 1, 0, 50000, 1536, 1);
    }
    gru_rec<<<256, 512, 0, stream>>>(toks, gxv, nullptr, Bw, 49152, 8,
        wg_bhh, hfin, 2048, 0, 64, 0, 64);
  } else {
    // path B: time-chunked x-gate GEMM + 4-step recurrence, 16 rounds
    for (int tc = 0; tc < 64/TC; tc++) {
      gemm_gxu<<<dim3(128, 6, 2), 256, 0, stream>>>(
          nullptr, embed, toks, Bgw, wg_bih, wg_bhh, gxf, (long)8192*768, 2, tc*TC, 0, 768, 0);
      gru_rec<<<256, 512, 0, stream>>>(toks, gxf, gxb, Bw, 49152, 8,
          wg_bhh, hfin, 2048, tc*TC, TC, 1, 64);
    }
  }

  // sentence level: gx GEMM with dir-sum staging (mode 3 folds add2bf)
  gemm_gxu<<<dim3(32, 12, 1), 256, 0, stream>>>(
      nullptr, hfin, nullptr, Bg, sg_bih, sg_bhh, gxs, 0, 3, 0, 0, 1536, 0);
  gru_rec<<<8, 512, 0, stream>>>(nullptr, gxs, nullptr, Bs, 24576, 0,
      sg_bhh, hs, 64, 0, 32, 2, 32);

  // fused p_batch + r_stars + review-level gx rows (replaces gemm_nt16)
  pbrs_k<<<R_, 256, 0, stream>>>(hs, uf, uf_w, rfc_w1, rfc_b1, rfc_w2, rfc_b2,
                                 rg_wih, rg_bih, rg_bhh, gxr, out);

  // review level: persistent bi-GRU + p_stars
  rev_gru<<<2, 512, 0, stream>>>(gxr, Br, rg_bhh, doc);
  pstars_k<<<1, 128, 0, stream>>>(doc, pfc_w1, pfc_b1, pfc_w2, pfc_b2, out);
}

// Round 11
// 666.041 us; speedup vs baseline: 1.0707x; 1.0707x over previous
//
#include <hip/hip_runtime.h>
#include <math.h>

#define R_ 64
#define S_ 32
#define W_ 64
#define H_ 256
#define UF_ 20
#define TC 4        // time-chunk for path B

typedef short bf16x8 __attribute__((ext_vector_type(8)));
typedef float f32x4  __attribute__((ext_vector_type(4)));

#define MFMA(a,b,c) __builtin_amdgcn_mfma_f32_16x16x32_bf16((a),(b),(c),0,0,0)

typedef const unsigned int __attribute__((address_space(1)))* gp_t;
typedef unsigned int __attribute__((address_space(3)))* lp_t;
// async global->LDS DMA, 16B per lane, dest = wave-uniform base + lane*16
#define GLOAD16(SRC, DST) \
  __builtin_amdgcn_global_load_lds((gp_t)(const void*)(SRC), (lp_t)(void*)(DST), 16, 0, 0)

// hbf bank swizzle (rev_gru only)
#define SW(r) ((((r)>>1)&7)<<3)

// whh fragment ff: 0..39 register-resident, 40..47 in LDS (Bl)
#define BFRAG(ff) ((ff) < 40 ? Breg[(ff) < 40 ? (ff) : 0] \
                 : *(const bf16x8*)&Bl[w][(ff) >= 40 ? (ff)-40 : 0][l*8])

__device__ __forceinline__ float sigf(float x){ return 1.0f/(1.0f+__expf(-x)); }
__device__ __forceinline__ float tanhf_(float x){ float e=__expf(2.0f*x); return 1.0f-2.0f/(e+1.0f); }
__device__ __forceinline__ float seluf_(float x){
  const float sc=1.0507009873554805f, al=1.6732632423543772f;
  return x>0.0f ? sc*x : sc*al*(expf(x)-1.0f);
}
__device__ __forceinline__ short tobf(float f){
  unsigned u=__float_as_uint(f); u += 0x7fffu + ((u>>16)&1u); return (short)(u>>16);
}
__device__ __forceinline__ float bf2f(short s){
  return __uint_as_float(((unsigned)(unsigned short)s) << 16);
}
__device__ __forceinline__ unsigned pk2(float a, float b){
  return (unsigned)(unsigned short)tobf(a) | ((unsigned)(unsigned short)tobf(b) << 16);
}

// ---------------------------------------------------------------------------
// Weight-prep bodies (merged into one launch below)
// ---------------------------------------------------------------------------
__device__ __forceinline__ void prep_word_body(int idx, const float* wih,
                                               const float* whh, short* Bw)
{
  int lane = idx & 63;
  int rest = idx >> 6;
  int f  = rest % 6;  rest /= 6;
  int kt = rest % 16; rest /= 16;
  int w  = rest % 8;
  int d  = rest / 8;
  int gate = f >> 1;
  int j = 32*w + (f&1)*16 + (lane&15);
  int row = gate*256 + j;
  const float* W = (kt < 8 ? wih : whh) + (size_t)d*768*256;
  int k = (kt&7)*32 + (lane>>4)*8;
  short* dst = Bw + ((((size_t)(d*8 + w)*16 + kt)*6 + f)*64 + lane)*8;
#pragma unroll
  for (int jj=0;jj<8;jj++) dst[jj] = tobf(W[(size_t)row*256 + k + jj]);
}

__device__ __forceinline__ void prep_rnn_body(int idx, const float* whh, short* Bs)
{
  int lane = idx & 63;
  int rest = idx >> 6;
  int f  = rest % 6; rest /= 6;
  int kt = rest % 8; rest /= 8;
  int w  = rest % 8;
  int d  = rest / 8;
  int j = 32*w + (f&1)*16 + (lane&15);
  int row = (f>>1)*256 + j;
  const float* W = whh + (size_t)d*768*256;
  int k = kt*32 + (lane>>4)*8;
  short* dst = Bs + ((((size_t)(d*8 + w)*8 + kt)*6 + f)*64 + lane)*8;
#pragma unroll
  for (int jj=0;jj<8;jj++) dst[jj] = tobf(W[(size_t)row*256 + k + jj]);
}

__device__ __forceinline__ void prep_gemm_body(int idx, const float* Wsrc, short* Bg)
{
  int lane = idx & 63;
  int rest = idx >> 6;
  int kt = rest % 8;
  int nt = rest / 8;
  int n = nt*16 + (lane&15);
  int k = kt*32 + (lane>>4)*8;
  short* dst = Bg + (((size_t)nt*8 + kt)*64 + lane)*8;
#pragma unroll
  for (int jj=0;jj<8;jj++) dst[jj] = tobf(Wsrc[(size_t)n*256 + k + jj]);
}

__device__ __forceinline__ void prep_embb_body(int t, const float* E, short* O, int M)
{
  const int row = t >> 5, c0 = (t & 31)*8;
  const int r = row < M ? row : M - 1;
  const float* s = E + (size_t)r*256 + c0;
  float4 v0 = *(const float4*)(s);
  float4 v1 = *(const float4*)(s + 4);
  uint4 u;
  u.x = pk2(v0.x, v0.y); u.y = pk2(v0.z, v0.w);
  u.z = pk2(v1.x, v1.y); u.w = pk2(v1.z, v1.w);
  *(uint4*)&O[(size_t)row*256 + c0] = u;
}

// One launch for all weight preps + optional embed->bf16 convert.
// Block ranges: [0,384) word, [384,576) sent-rnn, [576,768) rev-rnn,
// [768,960) sent-gemm, [960,1152) word-gemm, [1152,1152+6256) embb.
__global__ void prep_all(const float* __restrict__ wg_wih, const float* __restrict__ wg_whh,
                         const float* __restrict__ sg_whh, const float* __restrict__ rg_whh,
                         const float* __restrict__ sg_wih, const float* __restrict__ embed,
                         short* __restrict__ Bw, short* __restrict__ Bs,
                         short* __restrict__ Br, short* __restrict__ Bg,
                         short* __restrict__ Bgw, short* __restrict__ embb)
{
  const int b = blockIdx.x, tid = threadIdx.x;
  if      (b <  384) prep_word_body( b       *256 + tid, wg_wih, wg_whh, Bw);
  else if (b <  576) prep_rnn_body ((b- 384)*256 + tid, sg_whh, Bs);
  else if (b <  768) prep_rnn_body ((b- 576)*256 + tid, rg_whh, Br);
  else if (b <  960) prep_gemm_body((b- 768)*256 + tid, sg_wih, Bg);
  else if (b < 1152) prep_gemm_body((b- 960)*256 + tid, wg_wih, Bgw);
  else               prep_embb_body((b-1152)*256 + tid, embed, embb, 50000);
}

// ---------------------------------------------------------------------------
// Unified MFMA gx GEMM (r5/r9-verified form), C bf16 = A[.,256] @ B^T + bias.
// Tile 64x128, 256 thr, natural grid order (x = m-tile fast).
// mode 0: A = bf16 contiguous rows (Ab)           (vocab embb)
// mode 1: A = fp32 rows of Af, clamped to Mclamp  (vocab fallback)
// mode 2: A = fp32 rows of Af gathered via token window (chunked, path B)
// mode 3: A = fp32 dir-sum rows: Af[r] + Af[r + 2048*256] (sentence gx,
//         folds the old add2bf kernel into the staging)
// ---------------------------------------------------------------------------
__global__ __launch_bounds__(256) void gemm_gxu(
    const short* __restrict__ Ab, const float* __restrict__ Af,
    const int* __restrict__ toks, const short* __restrict__ Bg,
    const float* __restrict__ bih, const float* __restrict__ bhh,
    short* __restrict__ C, long Czoff,
    int mode, int t0, int Mclamp, int Cstride)
{
  const int z  = blockIdx.z;
  const int m0 = blockIdx.x * 64;
  const int yt = blockIdx.y * 8;                    // C ntile base (dir-local)
  const int ntb = (mode == 2 ? z*48 : 0) + yt;      // B ntile base
  const int tid = threadIdx.x;
  const int w = tid >> 6, l = tid & 63;
  const int c = l & 15, q = l >> 4;
  __shared__ short As[64][264];
  {
    const int row = tid >> 2, c0 = (tid & 3) * 64;
    if (mode == 0) {
      const uint4* s = (const uint4*)(Ab + (size_t)(m0+row)*256 + c0);
#pragma unroll
      for (int i = 0; i < 8; i++) *(uint4*)&As[row][c0 + i*8] = s[i];
    } else if (mode == 3) {
      const float* s0 = Af + (size_t)(m0+row)*256 + c0;
      const float* s1 = s0 + (size_t)2048*256;
#pragma unroll
      for (int i = 0; i < 8; i++) {
        float4 a0 = *(const float4*)(s0 + i*8);
        float4 a1 = *(const float4*)(s0 + i*8 + 4);
        float4 b0 = *(const float4*)(s1 + i*8);
        float4 b1 = *(const float4*)(s1 + i*8 + 4);
        uint4 u;
        u.x = pk2(a0.x+b0.x, a0.y+b0.y); u.y = pk2(a0.z+b0.z, a0.w+b0.w);
        u.z = pk2(a1.x+b1.x, a1.y+b1.y); u.w = pk2(a1.z+b1.z, a1.w+b1.w);
        *(uint4*)&As[row][c0 + i*8] = u;
      }
    } else {
      int r;
      if (mode == 1) {
        r = m0 + row; if (r >= Mclamp) r = Mclamp - 1;
      } else {
        const int rr = m0 + row;
        const int s_ = rr / TC, i_ = rr % TC;
        const int wd = z ? (63 - (t0 + i_)) : (t0 + i_);
        r = toks[s_*64 + wd];
      }
      const float* s = Af + (size_t)r*256 + c0;
#pragma unroll
      for (int i = 0; i < 8; i++) {
        float4 v0 = *(const float4*)(s + i*8);
        float4 v1 = *(const float4*)(s + i*8 + 4);
        uint4 u;
        u.x = pk2(v0.x, v0.y); u.y = pk2(v0.z, v0.w);
        u.z = pk2(v1.x, v1.y); u.w = pk2(v1.z, v1.w);
        *(uint4*)&As[row][c0 + i*8] = u;
      }
    }
  }
  // per-thread bias for its 2 output columns
  float bias[2];
#pragma unroll
  for (int nt = 0; nt < 2; nt++) {
    const int coln = (yt + 2*w + nt)*16 + c;               // dir-local col
    const int bidx = (mode == 2 ? z*768 : 0) + coln;       // global col
    bias[nt] = bih[bidx] + ((bidx % 768) < 512 ? bhh[bidx] : 0.0f);
  }
  __syncthreads();
  f32x4 acc[4][2];
#pragma unroll
  for (int a = 0; a < 4; a++) { acc[a][0] = (f32x4)0.f; acc[a][1] = (f32x4)0.f; }
#pragma unroll
  for (int kt = 0; kt < 8; kt++) {
    const int ko = kt*32 + q*8;
    bf16x8 a0 = *(const bf16x8*)&As[ 0+c][ko];
    bf16x8 a1 = *(const bf16x8*)&As[16+c][ko];
    bf16x8 a2 = *(const bf16x8*)&As[32+c][ko];
    bf16x8 a3 = *(const bf16x8*)&As[48+c][ko];
    bf16x8 b0 = *(const bf16x8*)&Bg[(((size_t)(ntb + 2*w    )*8 + kt)*64 + l)*8];
    bf16x8 b1 = *(const bf16x8*)&Bg[(((size_t)(ntb + 2*w + 1)*8 + kt)*64 + l)*8];
    acc[0][0]=MFMA(a0,b0,acc[0][0]); acc[1][0]=MFMA(a1,b0,acc[1][0]);
    acc[2][0]=MFMA(a2,b0,acc[2][0]); acc[3][0]=MFMA(a3,b0,acc[3][0]);
    acc[0][1]=MFMA(a0,b1,acc[0][1]); acc[1][1]=MFMA(a1,b1,acc[1][1]);
    acc[2][1]=MFMA(a2,b1,acc[2][1]); acc[3][1]=MFMA(a3,b1,acc[3][1]);
  }
  short* Cz = C + (size_t)z * Czoff;
#pragma unroll
  for (int mt = 0; mt < 4; mt++)
#pragma unroll
  for (int nt = 0; nt < 2; nt++)
#pragma unroll
  for (int rg = 0; rg < 4; rg++)
    Cz[(size_t)(m0 + mt*16 + q*4 + rg)*Cstride + (yt + 2*w + nt)*16 + c] =
        tobf(acc[mt][nt][rg] + bias[nt]);
}

// ---------------------------------------------------------------------------
// gx staging DMA (r1 layout): wave w stages its row pair {2w, 2w+1}
// (2 x 1536B) of step tt into gbuf[buf] rows 2w,2w+1 (contiguous, unpadded).
// ---------------------------------------------------------------------------
__device__ __forceinline__ void stage_issue(
    short* dstbase,                 // &gbuf[buf][0][0]
    int mode, int d, int g, int w, int l,
    int nwords, int t0, int tt,
    const int* tokp, const short* gxF, const short* gxB)
{
  const char* bF = (const char*)gxF;
  const char* bB = (const char*)gxB;
#pragma unroll
  for (int i = 0; i < 3; i++) {
    const int off = i*1024 + l*16;          // byte within row pair (0..3071)
    const int rl  = (off >= 1536) ? 1 : 0;  // row within pair
    const int col = off - rl*1536;          // byte within row
    const char* src;
    if (mode == 0) {
      const int tx  = d ? (nwords - 1 - tt) : tt;
      const int tok = tokp[(2*w + rl)*64 + tx];
      src = bF + (size_t)tok*3072 + d*1536 + col;
    } else if (mode == 1) {
      const int ri = (g*16 + 2*w + rl)*TC + (tt - t0);
      src = (d ? bB : bF) + (size_t)ri*1536 + col;
    } else {
      const int se  = d ? (nwords - 1 - tt) : tt;
      const int row = g*16 + 2*w + rl;
      src = bF + ((size_t)row*nwords + se)*3072 + (size_t)d*1536 + col;
    }
    GLOAD16(src, dstbase + (size_t)w*1536 + i*512);
  }
}

// ---------------------------------------------------------------------------
// Unified bi-GRU recurrence — r1-verified structure (best measured: 222 µs)
// + bias folding (only bNH remains in-loop). whh fragments: 40 in registers,
// 8 in LDS. gx staged via async DMA issued ONE STEP AHEAD; __syncthreads'
// implicit vmcnt drain is the completion guarantee. Inline per-kt fragment
// reads and inline gbuf epilogue reads keep mid-loop register liveness
// minimal (the r2-r4 regressions came from preload arrays raising pressure).
// Block = (dir, group of 16 rows); 512 thr / 8 waves; one barrier per step.
// ---------------------------------------------------------------------------
__global__ __launch_bounds__(512, 2) void gru_rec(
    const int* __restrict__ toks,
    const short* __restrict__ gxF, const short* __restrict__ gxB,
    const short* __restrict__ Bh, int wstride, int koff,
    const float* __restrict__ bhh,
    float* __restrict__ hstate, int NS,
    int t0, int nsteps, int mode, int nwords)
{
  const int d = blockIdx.x & 1;
  const int g = blockIdx.x >> 1;
  const int tid = threadIdx.x;
  const int w = tid >> 6, l = tid & 63;
  const int c = l & 15, q = l >> 4;

  __shared__ short gbuf[2][16][768];    // UNPADDED: DMA dest must be linear
  __shared__ short hbf[2][16][264];
  __shared__ short Bl[8][8][512];       // whh fragments ff=40..47, per wave
  __shared__ int   tokL[1024];

  if (mode == 0)
    for (int i = tid; i < 1024; i += 512) tokL[i] = toks[(size_t)g*1024 + i];

  // whh fragments: 40 in registers, 8 in LDS
  bf16x8 Breg[40];
  {
    const short* Bb = Bh + (size_t)(d*8 + w)*wstride + (size_t)koff*3072 + l*8;
#pragma unroll
    for (int ff = 0; ff < 48; ff++) {
      bf16x8 v = *(const bf16x8*)(Bb + ff*512);
      if (ff < 40) Breg[ff] = v;
      else *(bf16x8*)&Bl[w][ff-40][l*8] = v;
    }
  }

  float bNH[2];
#pragma unroll
  for (int jt = 0; jt < 2; jt++)
    bNH[jt] = bhh[d*768 + 512 + 32*w + jt*16 + c];

  float hst[2][4];
  const int cur0 = t0 & 1;
  if (t0 == 0) {
#pragma unroll
    for (int a = 0; a < 2; a++)
#pragma unroll
    for (int r = 0; r < 4; r++) hst[a][r] = 0.0f;
  } else {
#pragma unroll
    for (int jt = 0; jt < 2; jt++)
#pragma unroll
    for (int rg = 0; rg < 4; rg++)
      hst[jt][rg] = hstate[((size_t)d*NS + g*16 + q*4 + rg)*256 + 32*w + jt*16 + c];
  }
#pragma unroll
  for (int jt = 0; jt < 2; jt++)
#pragma unroll
  for (int rg = 0; rg < 4; rg++)
    hbf[cur0][q*4 + rg][32*w + jt*16 + c] = tobf(hst[jt][rg]);

  // prologue stage of step t0 (mode 0 reads tokens from global; tokL not
  // yet visible before the barrier)
  stage_issue((short*)gbuf[cur0], mode, d, g, w, l, nwords, t0, t0,
              (mode == 0) ? toks + (size_t)g*1024 : (const int*)nullptr, gxF, gxB);

  __syncthreads();   // tokL + hbf + Bl init + prologue DMA all visible

  const int tend = t0 + nsteps;
  for (int t = t0; t < tend; t++) {
    const int cur = t & 1, nxt = 1 - cur;

    // issue NEXT step's gx DMA now; it completes during MFMA+epilogue and
    // the end-of-iter __syncthreads (vmcnt drain) guarantees visibility.
    if (t + 1 < tend)
      stage_issue((short*)gbuf[nxt], mode, d, g, w, l, nwords, t0, t + 1,
                  tokL, gxF, gxB);

    f32x4 accR[2], accZ[2], accNH[2];
#pragma unroll
    for (int a = 0; a < 2; a++) { accR[a]=(f32x4)0.f; accZ[a]=(f32x4)0.f; accNH[a]=(f32x4)0.f; }
#pragma unroll
    for (int kt = 0; kt < 8; kt++) {
      bf16x8 a0 = *(const bf16x8*)&hbf[cur][c][kt*32 + q*8];
      bf16x8 b0 = BFRAG(kt*6+0), b1 = BFRAG(kt*6+1), b2 = BFRAG(kt*6+2),
             b3 = BFRAG(kt*6+3), b4 = BFRAG(kt*6+4), b5 = BFRAG(kt*6+5);
      accR[0]=MFMA(a0,b0,accR[0]);  accR[1]=MFMA(a0,b1,accR[1]);
      accZ[0]=MFMA(a0,b2,accZ[0]);  accZ[1]=MFMA(a0,b3,accZ[1]);
      accNH[0]=MFMA(a0,b4,accNH[0]); accNH[1]=MFMA(a0,b5,accNH[1]);
    }

    // gates + state update (biases pre-folded into gx except bNH)
#pragma unroll
    for (int jt = 0; jt < 2; jt++)
#pragma unroll
    for (int rg = 0; rg < 4; rg++) {
      const int m = q*4 + rg;
      const int j = 32*w + jt*16 + c;
      const float gr = bf2f(gbuf[cur][m][j]);
      const float gz = bf2f(gbuf[cur][m][256 + j]);
      const float gn = bf2f(gbuf[cur][m][512 + j]);
      const float r = sigf(gr + accR[jt][rg]);
      const float z = sigf(gz + accZ[jt][rg]);
      const float n = tanhf_(gn + r*(accNH[jt][rg] + bNH[jt]));
      float h = hst[jt][rg];
      h = (1.0f - z)*n + z*h;
      hst[jt][rg] = h;
      hbf[nxt][m][j] = tobf(h);
    }
    __syncthreads();   // drains next-step DMA (vmcnt) + hbf[nxt] (lgkm)
  }

#pragma unroll
  for (int jt = 0; jt < 2; jt++)
#pragma unroll
  for (int rg = 0; rg < 4; rg++)
    hstate[((size_t)d*NS + g*16 + q*4 + rg)*256 + 32*w + jt*16 + c] = hst[jt][rg];
}

// ---------------------------------------------------------------------------
// Review-level bi-GRU, batch 1. Only row 0 is real: epilogue on q==0 lanes,
// hbf double-buffered -> single barrier per step. Biases pre-folded (bNH
// only). Grid 2.
// ---------------------------------------------------------------------------
__global__ __launch_bounds__(512, 2) void rev_gru(
    const float* __restrict__ gx, const short* __restrict__ Br,
    const float* __restrict__ bhh,
    float* __restrict__ doc)
{
  const int d = blockIdx.x;
  const int tid = threadIdx.x;
  const int w = tid >> 6, l = tid & 63;
  const int c = l & 15, q = l >> 4;
  const int j0 = 32*w + c;

  __shared__ short hbf[2][16][256];   // swizzled; rows >=1 stay zero
  __shared__ short Bl[8][8][512];
  for (int i = tid; i < 2*16*256; i += 512) ((short*)hbf)[i] = 0;

  bf16x8 Breg[40];
  {
    const short* Bbase = Br + (size_t)(d*8 + w)*8*6*512 + l*8;
#pragma unroll
    for (int ff = 0; ff < 48; ff++) {
      bf16x8 v = *(const bf16x8*)(Bbase + ff*512);
      if (ff < 40) Breg[ff] = v;
      else *(bf16x8*)&Bl[w][ff-40][l*8] = v;
    }
  }

  float bNH[2];
#pragma unroll
  for (int jt = 0; jt < 2; jt++)
    bNH[jt] = bhh[d*768 + 512 + j0 + jt*16];

  float hst[2];
  hst[0] = 0.0f; hst[1] = 0.0f;
  __syncthreads();

  for (int t = 0; t < 64; t++) {
    const int cur = t & 1, nxt = 1 - cur;
    const int teff = (d == 0) ? t : (63 - t);

    // prefetch this step's gates (row 0 only -> q==0 lanes)
    float G[2][3];
    if (q == 0) {
#pragma unroll
      for (int jt = 0; jt < 2; jt++) {
        const size_t row = (size_t)teff*1536 + d*768;
        const int j = j0 + jt*16;
        G[jt][0] = gx[row + j]; G[jt][1] = gx[row + 256 + j]; G[jt][2] = gx[row + 512 + j];
      }
    }

    f32x4 accR[2], accZ[2], accNH[2];
#pragma unroll
    for (int a=0;a<2;a++) { accR[a]=(f32x4)0.f; accZ[a]=(f32x4)0.f; accNH[a]=(f32x4)0.f; }
#pragma unroll
    for (int kt = 0; kt < 8; kt++) {
      bf16x8 a0 = *(const bf16x8*)&hbf[cur][c][(kt*32 + q*8) ^ SW(c)];
      bf16x8 b0 = BFRAG(kt*6+0), b1 = BFRAG(kt*6+1), b2 = BFRAG(kt*6+2),
             b3 = BFRAG(kt*6+3), b4 = BFRAG(kt*6+4), b5 = BFRAG(kt*6+5);
      accR[0]=MFMA(a0,b0,accR[0]);  accR[1]=MFMA(a0,b1,accR[1]);
      accZ[0]=MFMA(a0,b2,accZ[0]);  accZ[1]=MFMA(a0,b3,accZ[1]);
      accNH[0]=MFMA(a0,b4,accNH[0]); accNH[1]=MFMA(a0,b5,accNH[1]);
    }

    if (q == 0) {
#pragma unroll
      for (int jt = 0; jt < 2; jt++) {
        const float r = sigf(G[jt][0] + accR[jt][0]);
        const float z = sigf(G[jt][1] + accZ[jt][0]);
        const float n = tanhf_(G[jt][2] + r*(accNH[jt][0] + bNH[jt]));
        const float h = n + z*(hst[jt] - n);
        hst[jt] = h;
        hbf[nxt][0][j0 + jt*16] = tobf(h);   // row 0: SW(0)=0
      }
    }
    __syncthreads();
  }
  if (q == 0) {
#pragma unroll
    for (int jt = 0; jt < 2; jt++)
      doc[d*256 + j0 + jt*16] = hst[jt];
  }
}

// ---------------------------------------------------------------------------
// fp32 GEMM + bias, BM=16/BN=64 (review-level gx, K=276). Bias folded here.
// ---------------------------------------------------------------------------
__global__ __launch_bounds__(256) void gemm_nt16(
    const float* __restrict__ A, const float* __restrict__ B,
    const float* __restrict__ bih, const float* __restrict__ bhh,
    float* __restrict__ C, int M, int N, int K)
{
  const int m0 = blockIdx.x * 16;
  const int n0 = blockIdx.y * 64;
  const int tid = threadIdx.x;
  __shared__ float As[16][17];
  __shared__ float Bs[16][68];
  float acc[4] = {0,0,0,0};
  const int m  = tid >> 4, n4 = (tid & 15) * 4;
  const int bn = tid >> 2, bk = (tid & 3) * 4;
  for (int k0 = 0; k0 < K; k0 += 16) {
    const int ak = tid & 15;
    float av = (k0 + ak < K) ? A[(size_t)(m0+m)*K + k0 + ak] : 0.0f;
    float4 b4 = make_float4(0,0,0,0);
    if (k0 + bk < K) b4 = *(const float4*)&B[(size_t)(n0+bn)*K + k0 + bk];
    __syncthreads();
    As[ak][m] = av;
    Bs[bk+0][bn]=b4.x; Bs[bk+1][bn]=b4.y; Bs[bk+2][bn]=b4.z; Bs[bk+3][bn]=b4.w;
    __syncthreads();
#pragma unroll
    for (int k = 0; k < 16; k++) {
      const float a = As[k][m];
      const float4 bb = *(const float4*)&Bs[k][n4];
      acc[0]+=a*bb.x; acc[1]+=a*bb.y; acc[2]+=a*bb.z; acc[3]+=a*bb.w;
    }
  }
#pragma unroll
  for (int i = 0; i < 4; i++) {
    const int n = n0 + n4 + i;
    acc[i] += bih[n] + ((n % 768) < 512 ? bhh[n] : 0.0f);
  }
  *(float4*)&C[(size_t)(m0+m)*N + n0+n4] = make_float4(acc[0],acc[1],acc[2],acc[3]);
}

// ---------------------------------------------------------------------------
// Fused p_batch + r_stars: block r builds pb row r (kept in LDS + written to
// global for the review-level GEMM), then computes r_stars for that review.
// ---------------------------------------------------------------------------
__global__ void pbrs_k(const float* __restrict__ hs, const float* __restrict__ uf,
                       const float* __restrict__ ufw,
                       const float* __restrict__ w1, const float* __restrict__ b1,
                       const float* __restrict__ w2, const float* __restrict__ b2,
                       float* __restrict__ pb, float* __restrict__ out)
{
  const int r = blockIdx.x, tid = threadIdx.x;   // 256 threads
  __shared__ float ps[276];
  __shared__ float s1[128];
  __shared__ float nrm;
  if (tid == 0) {
    float s = 0.f;
    for (int i = 0; i < UF_; i++) { const float v = uf[r*UF_ + i]; s += v*v; }
    nrm = fmaxf(sqrtf(s), 1e-12f);
  }
  __syncthreads();
  if (tid < H_) {
    const float v = hs[r*H_ + tid] + hs[(size_t)R_*H_ + r*H_ + tid];
    ps[tid] = v; pb[r*276 + tid] = v;
  }
  if (tid < UF_) {
    const float v = uf[r*UF_ + tid] / nrm * ufw[tid];
    ps[H_ + tid] = v; pb[r*276 + H_ + tid] = v;
  }
  __syncthreads();
  if (tid < 128) {
    float a = b1[tid];
    for (int k = 0; k < 276; k++) a += ps[k] * w1[tid*276 + k];
    s1[tid] = seluf_(a);
  }
  __syncthreads();
  if (tid == 0) {
    float s = b2[0];
    for (int k = 0; k < 128; k++) s += s1[k] * w2[k];
    out[9 + r] = s;
  }
}

// p_stars (doc dir-sum folded in: dc = doc2[0:256] + doc2[256:512])
__global__ void pstars_k(const float* __restrict__ doc2,
                         const float* __restrict__ w1, const float* __restrict__ b1,
                         const float* __restrict__ w2, const float* __restrict__ b2,
                         float* __restrict__ out)
{
  const int tid = threadIdx.x;   // 128 threads
  __shared__ float dc[256];
  __shared__ float s1[128];
  dc[tid]       = doc2[tid]       + doc2[256 + tid];
  dc[128 + tid] = doc2[128 + tid] + doc2[384 + tid];
  __syncthreads();
  float a = b1[tid];
  for (int k = 0; k < 256; k++) a += dc[k] * w1[tid*256 + k];
  s1[tid] = seluf_(a);
  __syncthreads();
  if (tid < 9) {
    float s = b2[tid];
    for (int k = 0; k < 128; k++) s += s1[k] * w2[tid*128 + k];
    out[tid] = s;
  }
}

// ---------------------------------------------------------------------------
extern "C" void kernel_launch(void* const* d_in, const int* in_sizes, int n_in,
                              void* d_out, int out_size, void* d_ws, size_t ws_size,
                              hipStream_t stream)
{
  const int*   toks   = (const int*)  d_in[0];
  const float* uf     = (const float*)d_in[3];
  const float* embed  = (const float*)d_in[4];
  const float* wg_wih = (const float*)d_in[5];
  const float* wg_whh = (const float*)d_in[6];
  const float* wg_bih = (const float*)d_in[7];
  const float* wg_bhh = (const float*)d_in[8];
  const float* sg_wih = (const float*)d_in[9];
  const float* sg_whh = (const float*)d_in[10];
  const float* sg_bih = (const float*)d_in[11];
  const float* sg_bhh = (const float*)d_in[12];
  const float* rg_wih = (const float*)d_in[13];
  const float* rg_whh = (const float*)d_in[14];
  const float* rg_bih = (const float*)d_in[15];
  const float* rg_bhh = (const float*)d_in[16];
  const float* rfc_w1 = (const float*)d_in[17];
  const float* rfc_b1 = (const float*)d_in[18];
  const float* rfc_w2 = (const float*)d_in[19];
  const float* rfc_b2 = (const float*)d_in[20];
  const float* pfc_w1 = (const float*)d_in[21];
  const float* pfc_b1 = (const float*)d_in[22];
  const float* pfc_w2 = (const float*)d_in[23];
  const float* pfc_b2 = (const float*)d_in[24];
  const float* uf_w   = (const float*)d_in[25];
  float* out = (float*)d_out;
  float* ws  = (float*)d_ws;
  (void)in_sizes; (void)n_in; (void)out_size;

  // workspace layout (float offsets)
  const size_t OFF_BW   = 0;                         // 393,216
  const size_t OFF_BS   = OFF_BW  + 393216;          // 196,608
  const size_t OFF_BR   = OFF_BS  + 196608;          // 196,608
  const size_t OFF_BG   = OFF_BR  + 196608;          // 196,608
  const size_t OFF_BGW  = OFF_BG  + 196608;          // 196,608
  const size_t OFF_HF   = OFF_BGW + 196608;          // 1,048,576
  const size_t OFF_SB   = OFF_HF  + 1048576;         // 262,144 (unused, kept)
  const size_t OFF_GXS  = OFF_SB  + 262144;          // 1,572,864 (bf16 2048x1536)
  const size_t OFF_HS   = OFF_GXS + 1572864;         // 32,768
  const size_t OFF_PB   = OFF_HS  + 32768;           // 17,664
  const size_t OFF_GXR  = OFF_PB  + 17664;           // 98,304
  const size_t OFF_DOC  = OFF_GXR + 98304;           // 512
  const size_t OFF_GXT  = OFF_DOC + 512;             // B: 2x 8192x768 bf16 = 6,291,456 f
  const size_t TOT_A    = OFF_GXT + (size_t)50048*1536/2;   // gxv bf16
  const size_t OFF_EMB  = TOT_A;                     // embb bf16 50048x256
  const size_t TOT_B    = TOT_A + (size_t)50048*256/2;

  short* Bw   = (short*)(ws + OFF_BW);
  short* Bs   = (short*)(ws + OFF_BS);
  short* Br   = (short*)(ws + OFF_BR);
  short* Bg   = (short*)(ws + OFF_BG);
  short* Bgw  = (short*)(ws + OFF_BGW);
  float* hfin = ws + OFF_HF;
  short* gxs  = (short*)(ws + OFF_GXS);
  float* hs   = ws + OFF_HS;
  float* pb   = ws + OFF_PB;
  float* gxr  = ws + OFF_GXR;
  float* doc  = ws + OFF_DOC;
  short* gxf  = (short*)(ws + OFF_GXT);
  short* gxb  = gxf + (size_t)8192*768;
  short* gxv  = (short*)(ws + OFF_GXT);
  short* embb = (short*)(ws + OFF_EMB);

  const bool bigger = ws_size >= TOT_B * sizeof(float);   // room for embb
  const bool big    = ws_size >= TOT_A * sizeof(float);

  // all weight preps (+ embed->bf16 when used) in ONE launch
  prep_all<<<1152 + (bigger ? 6256 : 0), 256, 0, stream>>>(
      wg_wih, wg_whh, sg_whh, rg_whh, sg_wih, embed,
      Bw, Bs, Br, Bg, Bgw, embb);

  if (big) {
    // path A: per-vocab x-gates (bf16, bias-folded), r9-verified grid (782,12)
    if (bigger) {
      gemm_gxu<<<dim3(782, 12, 1), 256, 0, stream>>>(
          embb, nullptr, nullptr, Bgw, wg_bih, wg_bhh, gxv, 0, 0, 0, 0, 1536);
    } else {
      gemm_gxu<<<dim3(782, 12, 1), 256, 0, stream>>>(
          nullptr, embed, nullptr, Bgw, wg_bih, wg_bhh, gxv, 0, 1, 0, 50000, 1536);
    }
    gru_rec<<<256, 512, 0, stream>>>(toks, gxv, nullptr, Bw, 49152, 8,
        wg_bhh, hfin, 2048, 0, 64, 0, 64);
  } else {
    // path B: time-chunked x-gate GEMM + 4-step recurrence, 16 rounds
    for (int tc = 0; tc < 64/TC; tc++) {
      gemm_gxu<<<dim3(128, 6, 2), 256, 0, stream>>>(
          nullptr, embed, toks, Bgw, wg_bih, wg_bhh, gxf, (long)8192*768, 2, tc*TC, 0, 768);
      gru_rec<<<256, 512, 0, stream>>>(toks, gxf, gxb, Bw, 49152, 8,
          wg_bhh, hfin, 2048, tc*TC, TC, 1, 64);
    }
  }

  // sentence level: gx GEMM with dir-sum staging (mode 3 folds add2bf)
  gemm_gxu<<<dim3(32, 12, 1), 256, 0, stream>>>(
      nullptr, hfin, nullptr, Bg, sg_bih, sg_bhh, gxs, 0, 3, 0, 0, 1536);
  gru_rec<<<8, 512, 0, stream>>>(nullptr, gxs, nullptr, Bs, 24576, 0,
      sg_bhh, hs, 64, 0, 32, 2, 32);

  // fused p_batch + r_stars
  pbrs_k<<<R_, 256, 0, stream>>>(hs, uf, uf_w, rfc_w1, rfc_b1, rfc_w2, rfc_b2, pb, out);

  // review level: fp32 gx GEMM (bias-folded) + persistent bi-GRU + p_stars
  gemm_nt16<<<dim3(4, 24), 256, 0, stream>>>(pb, rg_wih, rg_bih, rg_bhh, gxr, 64, 1536, 276);
  rev_gru<<<2, 512, 0, stream>>>(gxr, Br, rg_bhh, doc);
  pstars_k<<<1, 128, 0, stream>>>(doc, pfc_w1, pfc_b1, pfc_w2, pfc_b2, out);
}